// Round 4
// baseline (1095.122 us; speedup 1.0000x reference)
//
#include <hip/hip_runtime.h>

#define NF 40
#define NF4 10
#define H  64
#define NC 3
#define BK 256        // nodes per bucket (dst>>8)
#define CAP 10240     // staging capacity per bucket (mean 8184, +22 sigma)
#define NSL 8         // src slices of 16384 rows (2.6 MB of x) -> L2-resident phase
#define SSHIFT 14
#define NSEG 9        // 8 slice starts + end

// --- zero ints ---
__global__ void k_zero(int* __restrict__ p, int n) {
    int i = blockIdx.x * blockDim.x + threadIdx.x;
    if (i < n) p[i] = 0;
}

// --- partition edges into fixed-capacity bucket streams; edges register-cached ---
__global__ __launch_bounds__(256) void k_bin(const int* __restrict__ src,
                                             const int* __restrict__ dst,
                                             int* __restrict__ gcur,
                                             unsigned* __restrict__ staging,
                                             int ne, int nbk) {
    __shared__ int lh[512];
    __shared__ int lcur[512];
    int t = threadIdx.x;
    for (int b = t; b < nbk; b += 256) lh[b] = 0;
    __syncthreads();
    int gtid = blockIdx.x * 256 + t;
    int NT = gridDim.x * 256;
    int bk[13]; unsigned ed[13];
    #pragma unroll
    for (int u = 0; u < 13; ++u) {                 // 13*262144 > 3.2M: full coverage
        int i = gtid + u * NT;
        bool v = (i < ne);
        int dv = v ? dst[i] : 0;
        int sv = v ? src[i] : 0;
        bk[u] = v ? (dv >> 8) : -1;
        ed[u] = ((unsigned)(dv & 255) << 20) | (unsigned)sv;
        if (v) atomicAdd(&lh[dv >> 8], 1);
    }
    for (int i = gtid + 13 * NT; i < ne; i += NT)  // safety tail (0 iters here)
        atomicAdd(&lh[dst[i] >> 8], 1);
    __syncthreads();
    for (int b = t; b < nbk; b += 256)
        lcur[b] = lh[b] ? atomicAdd(&gcur[b], lh[b]) : 0;   // bucket-local base
    __syncthreads();
    #pragma unroll
    for (int u = 0; u < 13; ++u) {
        if (bk[u] >= 0) {
            int p = atomicAdd(&lcur[bk[u]], 1);
            staging[(size_t)bk[u] * CAP + p] = ed[u];
        }
    }
    for (int i = gtid + 13 * NT; i < ne; i += NT) {
        int dv = dst[i], sv = src[i]; int b = dv >> 8;
        int p = atomicAdd(&lcur[b], 1);
        staging[(size_t)b * CAP + p] = ((unsigned)(dv & 255) << 20) | (unsigned)sv;
    }
}

// --- per-bucket in-place sort by (slice, dlocal); emits dinv + slice boundaries ---
__global__ __launch_bounds__(512) void k_sort(unsigned* __restrict__ staging,
                                              const int* __restrict__ gcur,
                                              int* __restrict__ sseg,
                                              float* __restrict__ dinv, int n) {
    __shared__ unsigned buf[CAP];      // 40 KB bounce buffer
    __shared__ int cnt[NSL * BK];      // 2048: histogram -> cursors (in place)
    int b = blockIdx.x, t = threadIdx.x;
    int ebase = b * CAP;
    int rlen = gcur[b];
    for (int j = t; j < rlen; j += 512) buf[j] = staging[ebase + j];
    for (int i = t; i < NSL * BK; i += 512) cnt[i] = 0;
    __syncthreads();
    for (int j = t; j < rlen; j += 512) {
        unsigned e = buf[j];
        int key = (int)(((e & 0xFFFFFu) >> SSHIFT) * BK + (e >> 20));
        atomicAdd(&cnt[key], 1);
    }
    __syncthreads();
    if (t < BK) {                      // degrees -> dinv (before cnt is overwritten)
        int node = b * BK + t;
        if (node < n) {
            int deg = 0;
            #pragma unroll
            for (int k = 0; k < NSL; ++k) deg += cnt[k * BK + t];
            dinv[node] = rsqrtf((float)(deg + 1));
        }
    }
    __syncthreads();
    if (t < 64) {                      // single-wave exclusive scan of 2048, in place
        int lo = t * 32;
        int loc[32];
        int run = 0;
        #pragma unroll
        for (int i = 0; i < 32; ++i) { loc[i] = run; run += cnt[lo + i]; }
        int inc = run;
        #pragma unroll
        for (int off = 1; off < 64; off <<= 1) {
            int v = __shfl_up(inc, off);
            if (t >= off) inc += v;
        }
        int excl = inc - run;          // exclusive lane base
        #pragma unroll
        for (int i = 0; i < 32; ++i) cnt[lo + i] = ebase + excl + loc[i];
    }
    __syncthreads();
    if (t < NSL) sseg[b * NSEG + t] = cnt[t * BK];
    if (t == NSL) sseg[b * NSEG + NSL] = ebase + rlen;
    __syncthreads();
    for (int j = t; j < rlen; j += 512) {   // scatter: in-place sorted write-back
        unsigned e = buf[j];
        int key = (int)(((e & 0xFFFFFu) >> SSHIFT) * BK + (e >> 20));
        int p = atomicAdd(&cnt[key], 1);
        staging[p] = e;
    }
}

// --- conv1 aggregate: slice-phased gather, LDS accumulator; ax = dd*(sum + self) ---
__global__ __launch_bounds__(1024) void k_agg1(const unsigned* __restrict__ staging,
                                               const int* __restrict__ sseg,
                                               const float* __restrict__ dinv,
                                               const float4* __restrict__ x4,
                                               float* __restrict__ ax, int n) {
    __shared__ float axl[BK * NF];     // 40 KB accumulator
    __shared__ float ddv[BK];
    __shared__ int ss[NSEG];
    int b = blockIdx.x, t = threadIdx.x;
    if (t < NSEG) ss[t] = sseg[b * NSEG + t];
    if (t >= 64 && t < 64 + BK) {
        int d = t - 64; int node = b * BK + d;
        ddv[d] = (node < n) ? dinv[node] : 0.f;
    }
    __syncthreads();
    const float* x = (const float*)x4;
    for (int i = t; i < BK * NF; i += 1024) {      // self-term init (no zeroing pass)
        int d = i / NF, f = i - d * NF;
        int node = b * BK + d;
        axl[i] = (node < n) ? x[node * NF + f] * ddv[d] : 0.f;
    }
    __syncthreads();
    int G = t >> 4, r = t & 15;        // 64 edge-groups x 16 lanes (10 active float4)
    #pragma unroll 1
    for (int k = 0; k < NSL; ++k) {    // phase k: gathers confined to 2.6 MB x-slice
        for (int j = ss[k] + G; j < ss[k + 1]; j += 64) {
            unsigned e = staging[j];
            int s = (int)(e & 0xFFFFFu);
            int d = (int)(e >> 20);
            float w = dinv[s];
            if (r < NF4) {
                float4 xv = x4[s * NF4 + r];
                int base = d * NF + r * 4;
                atomicAdd(&axl[base + 0], xv.x * w);
                atomicAdd(&axl[base + 1], xv.y * w);
                atomicAdd(&axl[base + 2], xv.z * w);
                atomicAdd(&axl[base + 3], xv.w * w);
            }
        }
    }
    __syncthreads();
    for (int i = t; i < BK * NF; i += 1024) {
        int d = i / NF;
        int node = b * BK + d;
        if (node < n) ax[node * NF + (i - d * NF)] = axl[i] * ddv[d];
    }
}

// --- fused per-node MLP: h=relu(ax*W1+b1); spike=(h*Wf+bf>=0.5); s2sp=spike*W2*dinv ---
__global__ __launch_bounds__(256) void k_node(
        const float* __restrict__ ax,
        const float* __restrict__ W1, const float* __restrict__ b1,
        const float* __restrict__ Wf, const float* __restrict__ bf,
        const float* __restrict__ W2, const float* __restrict__ dinv,
        float* __restrict__ s2sp, int n) {
    __shared__ float lW1[NF * H];
    __shared__ float lWf[H * H];
    __shared__ float lW2[H * NC];
    __shared__ float lb1[H];
    __shared__ float lbf[H];
    __shared__ float lax[4][NF];
    __shared__ float lh[4][H];
    int t = threadIdx.x;
    for (int i = t; i < NF * H; i += 256) lW1[i] = W1[i];
    for (int i = t; i < H * H;  i += 256) lWf[i] = Wf[i];
    if (t < H * NC) lW2[t] = W2[t];
    if (t < H) { lb1[t] = b1[t]; lbf[t] = bf[t]; }
    __syncthreads();

    int w = t >> 6, lane = t & 63;
    for (int it = 0; it < 8; ++it) {
        int node = blockIdx.x * 32 + w * 8 + it;
        if (node >= n) break;

        if (lane < NF) lax[w][lane] = ax[node * NF + lane];
        float acc = lb1[lane];
        #pragma unroll
        for (int k = 0; k < NF; ++k) acc += lax[w][k] * lW1[k * H + lane];
        float h = fmaxf(acc, 0.0f);
        lh[w][lane] = h;

        float mem = lbf[lane];
        #pragma unroll
        for (int k = 0; k < H; ++k) mem += lh[w][k] * lWf[k * H + lane];
        float spike = (mem >= 0.5f) ? 1.0f : 0.0f;

        float v0 = spike * lW2[lane * NC + 0];
        float v1 = spike * lW2[lane * NC + 1];
        float v2 = spike * lW2[lane * NC + 2];
        for (int off = 32; off; off >>= 1) {
            v0 += __shfl_down(v0, off);
            v1 += __shfl_down(v1, off);
            v2 += __shfl_down(v2, off);
        }
        if (lane == 0) {
            float di = dinv[node];
            s2sp[node * 4 + 0] = v0 * di;
            s2sp[node * 4 + 1] = v1 * di;
            s2sp[node * 4 + 2] = v2 * di;
            s2sp[node * 4 + 3] = 0.0f;
        }
    }
}

// --- conv2 aggregate from staging + fused bias/filter; exclusive per-bucket writes ---
__global__ __launch_bounds__(512) void k_agg2(const unsigned* __restrict__ staging,
                                              const int* __restrict__ gcur,
                                              const float* __restrict__ dinv,
                                              const float4* __restrict__ s2sp4,
                                              const float* __restrict__ b2,
                                              const float* __restrict__ ef,
                                              float* __restrict__ out, int n) {
    __shared__ float o[BK * 4];
    int b = blockIdx.x, t = threadIdx.x;
    int ebase = b * CAP, rlen = gcur[b];
    for (int i = t; i < BK * 4; i += 512) o[i] = 0.f;
    __syncthreads();
    for (int j = t; j < rlen; j += 512) {
        unsigned e = staging[ebase + j];
        int s = (int)(e & 0xFFFFFu);
        int d = (int)(e >> 20);
        float4 v = s2sp4[s];               // 1.6 MB total: L2-resident gather
        atomicAdd(&o[d * 4 + 0], v.x);
        atomicAdd(&o[d * 4 + 1], v.y);
        atomicAdd(&o[d * 4 + 2], v.z);
    }
    __syncthreads();
    if (t < BK) {
        int node = b * BK + t;
        if (node < n) {
            float dd = dinv[node];
            float4 self = s2sp4[node];
            out[node * NC + 0] = (dd * (o[t * 4 + 0] + self.x) + b2[0]) * ef[0];
            out[node * NC + 1] = (dd * (o[t * 4 + 1] + self.y) + b2[1]) * ef[1];
            out[node * NC + 2] = (dd * (o[t * 4 + 2] + self.z) + b2[2]) * ef[2];
        }
    }
}

extern "C" void kernel_launch(void* const* d_in, const int* in_sizes, int n_in,
                              void* d_out, int out_size, void* d_ws, size_t ws_size,
                              hipStream_t stream) {
    const float* x  = (const float*)d_in[0];
    const int*   ei = (const int*)d_in[1];
    const float* W1 = (const float*)d_in[2];
    const float* b1 = (const float*)d_in[3];
    const float* Wf = (const float*)d_in[4];
    const float* bf = (const float*)d_in[5];
    const float* W2 = (const float*)d_in[6];
    const float* b2 = (const float*)d_in[7];
    const float* ef = (const float*)d_in[8];

    int n  = in_sizes[0] / NF;
    int ne = in_sizes[1] / 2;
    const int* src = ei;
    const int* dst = ei + ne;
    int nbk = (n + BK - 1) >> 8;               // 391

    auto al = [](size_t v) { return (v + 255) & ~(size_t)255; };
    char* ws = (char*)d_ws;
    size_t off = 0;
    unsigned* staging = (unsigned*)(ws + off); off += al((size_t)nbk * CAP * 4);   // 16 MB
    float*    axbuf   = (float*)(ws + off);    off += al((size_t)n * NF * 4);      // 16 MB
    float*    s2sp    = (float*)(ws + off);    off += al((size_t)n * 4 * 4);
    float*    dinv    = (float*)(ws + off);    off += al((size_t)n * 4);
    int*      sseg    = (int*)(ws + off);      off += al((size_t)nbk * NSEG * 4);
    int*      gcur    = (int*)(ws + off);      off += al((size_t)nbk * 4);
    float* out = (float*)d_out;

    k_zero <<<(nbk + 255) / 256, 256, 0, stream>>>(gcur, nbk);
    k_bin  <<<1024, 256, 0, stream>>>(src, dst, gcur, staging, ne, nbk);
    k_sort <<<nbk, 512, 0, stream>>>(staging, gcur, sseg, dinv, n);
    k_agg1 <<<nbk, 1024, 0, stream>>>(staging, sseg, dinv, (const float4*)x, axbuf, n);
    k_node <<<(n + 31) / 32, 256, 0, stream>>>(axbuf, W1, b1, Wf, bf, W2, dinv, s2sp, n);
    k_agg2 <<<nbk, 512, 0, stream>>>(staging, gcur, dinv, (const float4*)s2sp,
                                     b2, ef, out, n);
}

// Round 5
// 275.090 us; speedup vs baseline: 3.9810x; 3.9810x over previous
//
#include <hip/hip_runtime.h>

#define NF 40
#define NF4 10
#define H  64
#define NC 3
#define BK 256        // nodes per bucket (dst>>8)
#define CAP 10240     // staging capacity per bucket (mean 8192, +22 sigma)
#define MAXNBK 512
#define SMASK 0xFFFFFu

// --- zero ints ---
__global__ void k_zero(int* __restrict__ p, int n) {
    int i = blockIdx.x * blockDim.x + threadIdx.x;
    if (i < n) p[i] = 0;
}

// --- partition edges into fixed-capacity bucket streams; edges register-cached ---
__global__ __launch_bounds__(1024) void k_bin(const int* __restrict__ src,
                                              const int* __restrict__ dst,
                                              int* __restrict__ gcur,
                                              unsigned* __restrict__ staging,
                                              int ne, int nbk) {
    __shared__ int lh[MAXNBK];
    __shared__ int lcur[MAXNBK];
    int t = threadIdx.x;
    for (int b = t; b < nbk; b += 1024) lh[b] = 0;
    __syncthreads();
    int gtid = blockIdx.x * 1024 + t;
    int NT = gridDim.x * 1024;                     // 262144
    int bk[13]; unsigned ed[13];
    #pragma unroll
    for (int u = 0; u < 13; ++u) {                 // 13*262144 >= 3.2M: full coverage
        int i = gtid + u * NT;
        bool v = (i < ne);
        int dv = v ? dst[i] : 0;
        int sv = v ? src[i] : 0;
        bk[u] = v ? (dv >> 8) : -1;
        ed[u] = ((unsigned)(dv & 255) << 20) | (unsigned)sv;
        if (v) atomicAdd(&lh[dv >> 8], 1);
    }
    for (int i = gtid + 13 * NT; i < ne; i += NT)  // generic tail (0 iters here)
        atomicAdd(&lh[dst[i] >> 8], 1);
    __syncthreads();
    for (int b = t; b < nbk; b += 1024)
        lcur[b] = lh[b] ? atomicAdd(&gcur[b], lh[b]) : 0;   // reserve block's range
    __syncthreads();
    #pragma unroll
    for (int u = 0; u < 13; ++u) {
        if (bk[u] >= 0) {
            int p = atomicAdd(&lcur[bk[u]], 1);
            staging[(size_t)bk[u] * CAP + p] = ed[u];
        }
    }
    for (int i = gtid + 13 * NT; i < ne; i += NT) {
        int dv = dst[i], sv = src[i]; int b = dv >> 8;
        int p = atomicAdd(&lcur[b], 1);
        staging[(size_t)b * CAP + p] = ((unsigned)(dv & 255) << 20) | (unsigned)sv;
    }
}

// --- per-bucket sort by dlocal (in place via LDS bounce); emits rs/rl/dinv ---
__global__ __launch_bounds__(512) void k_sort(unsigned* __restrict__ staging,
                                              const int* __restrict__ gcur,
                                              int* __restrict__ rs, int* __restrict__ rl,
                                              float* __restrict__ dinv, int n) {
    __shared__ unsigned buf[CAP];      // 40 KB bounce buffer
    __shared__ int cnt[BK];
    __shared__ int scn[BK];
    __shared__ int cur[BK];
    int b = blockIdx.x, t = threadIdx.x;
    int ebase = b * CAP;
    int rlen = gcur[b];
    for (int j = t; j < rlen; j += 512) buf[j] = staging[ebase + j];
    if (t < BK) cnt[t] = 0;
    __syncthreads();
    for (int j = t; j < rlen; j += 512)
        atomicAdd(&cnt[buf[j] >> 20], 1);
    __syncthreads();
    if (t < BK) scn[t] = cnt[t];
    __syncthreads();
    for (int off = 1; off < BK; off <<= 1) {       // inclusive Hillis-Steele
        int a = (t < BK && t >= off) ? scn[t - off] : 0;
        __syncthreads();
        if (t < BK) scn[t] += a;
        __syncthreads();
    }
    if (t < BK) {
        int deg = cnt[t];
        int excl = scn[t] - deg;
        cur[t] = excl;
        int node = b * BK + t;
        if (node < n) {
            rs[node] = ebase + excl;
            rl[node] = deg;
            dinv[node] = rsqrtf((float)(deg + 1));
        }
    }
    __syncthreads();
    for (int j = t; j < rlen; j += 512) {          // scatter back sorted by dlocal
        unsigned e = buf[j];
        int p = atomicAdd(&cur[e >> 20], 1);
        staging[ebase + p] = e;
    }
}

// --- pull conv1: ax[d] = dd*(sum_s x[s]*dinv[s] + x[d]*dd); 6 nbr slots x 10 lanes ---
__global__ __launch_bounds__(256) void k_pull1(
        const unsigned* __restrict__ st, const int* __restrict__ rs,
        const int* __restrict__ rl, const float* __restrict__ dinv,
        const float4* __restrict__ x4, float4* __restrict__ ax4, int n) {
    __shared__ float4 red[4][64];
    int t = threadIdx.x;
    int w = t >> 6, lane = t & 63;
    int d = blockIdx.x * 4 + w;
    if (d >= n) return;
    int g = lane / 10, f = lane - g * 10;          // 6 slots x 10 float4-lanes
    int beg = rs[d], len = rl[d];
    float dd = dinv[d];
    float4 acc = make_float4(0.f, 0.f, 0.f, 0.f);
    if (g < 6) {
        int j = beg + g, end = beg + len;
        for (; j + 6 < end; j += 12) {             // 2 independent gathers in flight
            unsigned eA = st[j], eB = st[j + 6];
            int sA = (int)(eA & SMASK), sB = (int)(eB & SMASK);
            float wA = dinv[sA], wB = dinv[sB];
            float4 a4 = x4[sA * NF4 + f];
            float4 b4 = x4[sB * NF4 + f];
            acc.x += a4.x * wA + b4.x * wB;
            acc.y += a4.y * wA + b4.y * wB;
            acc.z += a4.z * wA + b4.z * wB;
            acc.w += a4.w * wA + b4.w * wB;
        }
        if (j < end) {
            unsigned e = st[j];
            int s = (int)(e & SMASK);
            float wv = dinv[s];
            float4 v = x4[s * NF4 + f];
            acc.x += v.x * wv; acc.y += v.y * wv;
            acc.z += v.z * wv; acc.w += v.w * wv;
        }
    }
    red[w][lane] = acc;
    // same-wave LDS RAW: compiler inserts lgkmcnt wait; no block barrier needed
    if (lane < NF4) {
        float4 tot = red[w][lane];
        #pragma unroll
        for (int gg = 1; gg < 6; ++gg) {
            float4 r = red[w][gg * 10 + lane];
            tot.x += r.x; tot.y += r.y; tot.z += r.z; tot.w += r.w;
        }
        float4 self = x4[d * NF4 + lane];
        float4 o;
        o.x = dd * (tot.x + self.x * dd);
        o.y = dd * (tot.y + self.y * dd);
        o.z = dd * (tot.z + self.z * dd);
        o.w = dd * (tot.w + self.w * dd);
        ax4[d * NF4 + lane] = o;
    }
}

// --- fused per-node MLP: h=relu(ax*W1+b1); spike=(h*Wf+bf>=0.5); s2sp=spike*W2*dinv ---
__global__ __launch_bounds__(256) void k_node(
        const float* __restrict__ ax,
        const float* __restrict__ W1, const float* __restrict__ b1,
        const float* __restrict__ Wf, const float* __restrict__ bf,
        const float* __restrict__ W2, const float* __restrict__ dinv,
        float* __restrict__ s2sp, int n) {
    __shared__ float lW1[NF * H];
    __shared__ float lWf[H * H];
    __shared__ float lW2[H * NC];
    __shared__ float lb1[H];
    __shared__ float lbf[H];
    __shared__ float lax[4][NF];
    __shared__ float lh[4][H];
    int t = threadIdx.x;
    for (int i = t; i < NF * H; i += 256) lW1[i] = W1[i];
    for (int i = t; i < H * H;  i += 256) lWf[i] = Wf[i];
    if (t < H * NC) lW2[t] = W2[t];
    if (t < H) { lb1[t] = b1[t]; lbf[t] = bf[t]; }
    __syncthreads();

    int w = t >> 6, lane = t & 63;
    for (int it = 0; it < 8; ++it) {               // 8 nodes/wave amortize staging
        int node = blockIdx.x * 32 + w * 8 + it;
        if (node >= n) break;

        if (lane < NF) lax[w][lane] = ax[node * NF + lane];
        float acc = lb1[lane];
        #pragma unroll
        for (int k = 0; k < NF; ++k) acc += lax[w][k] * lW1[k * H + lane];
        float h = fmaxf(acc, 0.0f);
        lh[w][lane] = h;

        float mem = lbf[lane];
        #pragma unroll
        for (int k = 0; k < H; ++k) mem += lh[w][k] * lWf[k * H + lane];
        float spike = (mem >= 0.5f) ? 1.0f : 0.0f;

        float v0 = spike * lW2[lane * NC + 0];
        float v1 = spike * lW2[lane * NC + 1];
        float v2 = spike * lW2[lane * NC + 2];
        for (int off = 32; off; off >>= 1) {
            v0 += __shfl_down(v0, off);
            v1 += __shfl_down(v1, off);
            v2 += __shfl_down(v2, off);
        }
        if (lane == 0) {
            float di = dinv[node];
            s2sp[node * 4 + 0] = v0 * di;
            s2sp[node * 4 + 1] = v1 * di;
            s2sp[node * 4 + 2] = v2 * di;
            s2sp[node * 4 + 3] = 0.0f;
        }
    }
}

// --- pull conv2 + bias + filter; one float4 gather per neighbor ---
__global__ __launch_bounds__(256) void k_pull2(
        const unsigned* __restrict__ st, const int* __restrict__ rs,
        const int* __restrict__ rl, const float* __restrict__ dinv,
        const float4* __restrict__ s2sp4, const float* __restrict__ b2,
        const float* __restrict__ ef, float* __restrict__ out, int n) {
    int t = threadIdx.x;
    int w = t >> 6, lane = t & 63;
    int d = blockIdx.x * 4 + w;
    if (d >= n) return;
    int beg = rs[d], end = beg + rl[d];
    float a0 = 0.f, a1 = 0.f, a2 = 0.f;
    for (int j = beg + lane; j < end; j += 64) {
        float4 v = s2sp4[st[j] & SMASK];           // 1.6 MB: L2-resident gather
        a0 += v.x; a1 += v.y; a2 += v.z;
    }
    for (int off = 32; off; off >>= 1) {
        a0 += __shfl_down(a0, off);
        a1 += __shfl_down(a1, off);
        a2 += __shfl_down(a2, off);
    }
    if (lane == 0) {
        float dd = dinv[d];
        float4 self = s2sp4[d];
        out[d * NC + 0] = (dd * (a0 + self.x) + b2[0]) * ef[0];
        out[d * NC + 1] = (dd * (a1 + self.y) + b2[1]) * ef[1];
        out[d * NC + 2] = (dd * (a2 + self.z) + b2[2]) * ef[2];
    }
}

extern "C" void kernel_launch(void* const* d_in, const int* in_sizes, int n_in,
                              void* d_out, int out_size, void* d_ws, size_t ws_size,
                              hipStream_t stream) {
    const float* x  = (const float*)d_in[0];
    const int*   ei = (const int*)d_in[1];
    const float* W1 = (const float*)d_in[2];
    const float* b1 = (const float*)d_in[3];
    const float* Wf = (const float*)d_in[4];
    const float* bf = (const float*)d_in[5];
    const float* W2 = (const float*)d_in[6];
    const float* b2 = (const float*)d_in[7];
    const float* ef = (const float*)d_in[8];

    int n  = in_sizes[0] / NF;
    int ne = in_sizes[1] / 2;
    const int* src = ei;
    const int* dst = ei + ne;
    int nbk = (n + BK - 1) >> 8;                   // 391

    auto al = [](size_t v) { return (v + 255) & ~(size_t)255; };
    char* ws = (char*)d_ws;
    size_t off = 0;
    unsigned* staging = (unsigned*)(ws + off); off += al((size_t)nbk * CAP * 4);   // 16 MB
    float*    axbuf   = (float*)(ws + off);    off += al((size_t)n * NF * 4);      // 16 MB
    float*    s2sp    = (float*)(ws + off);    off += al((size_t)n * 4 * 4);
    float*    dinv    = (float*)(ws + off);    off += al((size_t)n * 4);
    int*      rsb     = (int*)(ws + off);      off += al((size_t)n * 4);
    int*      rlb     = (int*)(ws + off);      off += al((size_t)n * 4);
    int*      gcur    = (int*)(ws + off);      off += al((size_t)MAXNBK * 4);
    float* out = (float*)d_out;

    k_zero <<<2, 256, 0, stream>>>(gcur, MAXNBK);
    k_bin  <<<256, 1024, 0, stream>>>(src, dst, gcur, staging, ne, nbk);
    k_sort <<<nbk, 512, 0, stream>>>(staging, gcur, rsb, rlb, dinv, n);
    k_pull1<<<(n + 3) / 4, 256, 0, stream>>>(staging, rsb, rlb, dinv,
                                             (const float4*)x, (float4*)axbuf, n);
    k_node <<<(n + 31) / 32, 256, 0, stream>>>(axbuf, W1, b1, Wf, bf, W2, dinv, s2sp, n);
    k_pull2<<<(n + 3) / 4, 256, 0, stream>>>(staging, rsb, rlb, dinv, (const float4*)s2sp,
                                             b2, ef, out, n);
}

// Round 6
// 257.382 us; speedup vs baseline: 4.2549x; 1.0688x over previous
//
#include <hip/hip_runtime.h>

#define NF 40
#define NF4 10
#define H  64
#define NC 3
#define BK 256        // nodes per bucket (dst>>8)
#define CAP 10240     // staging capacity per bucket (mean 8192, +22 sigma)
#define MAXNBK 512
#define SMASK 0xFFFFFu
#define NCHK 32       // nodes per wave in k_node

// --- zero ints ---
__global__ void k_zero(int* __restrict__ p, int n) {
    int i = blockIdx.x * blockDim.x + threadIdx.x;
    if (i < n) p[i] = 0;
}

// --- partition edges into fixed-capacity bucket streams; edges register-cached ---
__global__ __launch_bounds__(1024) void k_bin(const int* __restrict__ src,
                                              const int* __restrict__ dst,
                                              int* __restrict__ gcur,
                                              unsigned* __restrict__ staging,
                                              int ne, int nbk) {
    __shared__ int lh[MAXNBK];
    __shared__ int lcur[MAXNBK];
    int t = threadIdx.x;
    for (int b = t; b < nbk; b += 1024) lh[b] = 0;
    __syncthreads();
    int gtid = blockIdx.x * 1024 + t;
    int NT = gridDim.x * 1024;                     // 262144
    int bk[13]; unsigned ed[13];
    #pragma unroll
    for (int u = 0; u < 13; ++u) {                 // 13*262144 >= 3.2M: full coverage
        int i = gtid + u * NT;
        bool v = (i < ne);
        int dv = v ? dst[i] : 0;
        int sv = v ? src[i] : 0;
        bk[u] = v ? (dv >> 8) : -1;
        ed[u] = ((unsigned)(dv & 255) << 20) | (unsigned)sv;
        if (v) atomicAdd(&lh[dv >> 8], 1);
    }
    for (int i = gtid + 13 * NT; i < ne; i += NT)  // generic tail (0 iters here)
        atomicAdd(&lh[dst[i] >> 8], 1);
    __syncthreads();
    for (int b = t; b < nbk; b += 1024)
        lcur[b] = lh[b] ? atomicAdd(&gcur[b], lh[b]) : 0;   // reserve block's range
    __syncthreads();
    #pragma unroll
    for (int u = 0; u < 13; ++u) {
        if (bk[u] >= 0) {
            int p = atomicAdd(&lcur[bk[u]], 1);
            staging[(size_t)bk[u] * CAP + p] = ed[u];
        }
    }
    for (int i = gtid + 13 * NT; i < ne; i += NT) {
        int dv = dst[i], sv = src[i]; int b = dv >> 8;
        int p = atomicAdd(&lcur[b], 1);
        staging[(size_t)b * CAP + p] = ((unsigned)(dv & 255) << 20) | (unsigned)sv;
    }
}

// --- per-bucket sort by dlocal (in place via LDS bounce); emits rs/rl/dinv ---
__global__ __launch_bounds__(512) void k_sort(unsigned* __restrict__ staging,
                                              const int* __restrict__ gcur,
                                              int* __restrict__ rs, int* __restrict__ rl,
                                              float* __restrict__ dinv, int n) {
    __shared__ unsigned buf[CAP];      // 40 KB bounce buffer
    __shared__ int cnt[BK];
    __shared__ int scn[BK];
    __shared__ int cur[BK];
    int b = blockIdx.x, t = threadIdx.x;
    int ebase = b * CAP;
    int rlen = gcur[b];
    for (int j = t; j < rlen; j += 512) buf[j] = staging[ebase + j];
    if (t < BK) cnt[t] = 0;
    __syncthreads();
    for (int j = t; j < rlen; j += 512)
        atomicAdd(&cnt[buf[j] >> 20], 1);
    __syncthreads();
    if (t < BK) scn[t] = cnt[t];
    __syncthreads();
    for (int off = 1; off < BK; off <<= 1) {       // inclusive Hillis-Steele
        int a = (t < BK && t >= off) ? scn[t - off] : 0;
        __syncthreads();
        if (t < BK) scn[t] += a;
        __syncthreads();
    }
    if (t < BK) {
        int deg = cnt[t];
        int excl = scn[t] - deg;
        cur[t] = excl;
        int node = b * BK + t;
        if (node < n) {
            rs[node] = ebase + excl;
            rl[node] = deg;
            dinv[node] = rsqrtf((float)(deg + 1));
        }
    }
    __syncthreads();
    for (int j = t; j < rlen; j += 512) {          // scatter back sorted by dlocal
        unsigned e = buf[j];
        int p = atomicAdd(&cur[e >> 20], 1);
        staging[ebase + p] = e;
    }
}

// --- pull conv1: ax[d] = dd*(sum_s x[s]*dinv[s] + x[d]*dd); 6 nbr slots x 10 lanes ---
__global__ __launch_bounds__(256) void k_pull1(
        const unsigned* __restrict__ st, const int* __restrict__ rs,
        const int* __restrict__ rl, const float* __restrict__ dinv,
        const float4* __restrict__ x4, float4* __restrict__ ax4, int n) {
    __shared__ float4 red[4][64];
    int t = threadIdx.x;
    int w = t >> 6, lane = t & 63;
    int d = blockIdx.x * 4 + w;
    if (d >= n) return;
    int g = lane / 10, f = lane - g * 10;          // 6 slots x 10 float4-lanes
    int beg = rs[d], len = rl[d];
    float dd = dinv[d];
    float4 acc = make_float4(0.f, 0.f, 0.f, 0.f);
    if (g < 6) {
        int j = beg + g, end = beg + len;
        for (; j + 6 < end; j += 12) {             // 2 independent gathers in flight
            unsigned eA = st[j], eB = st[j + 6];
            int sA = (int)(eA & SMASK), sB = (int)(eB & SMASK);
            float wA = dinv[sA], wB = dinv[sB];
            float4 a4 = x4[sA * NF4 + f];
            float4 b4 = x4[sB * NF4 + f];
            acc.x += a4.x * wA + b4.x * wB;
            acc.y += a4.y * wA + b4.y * wB;
            acc.z += a4.z * wA + b4.z * wB;
            acc.w += a4.w * wA + b4.w * wB;
        }
        if (j < end) {
            unsigned e = st[j];
            int s = (int)(e & SMASK);
            float wv = dinv[s];
            float4 v = x4[s * NF4 + f];
            acc.x += v.x * wv; acc.y += v.y * wv;
            acc.z += v.z * wv; acc.w += v.w * wv;
        }
    }
    red[w][lane] = acc;
    // same-wave LDS RAW: in-order DS pipe + compiler lgkmcnt; no block barrier needed
    if (lane < NF4) {
        float4 tot = red[w][lane];
        #pragma unroll
        for (int gg = 1; gg < 6; ++gg) {
            float4 r = red[w][gg * 10 + lane];
            tot.x += r.x; tot.y += r.y; tot.z += r.z; tot.w += r.w;
        }
        float4 self = x4[d * NF4 + lane];
        float4 o;
        o.x = dd * (tot.x + self.x * dd);
        o.y = dd * (tot.y + self.y * dd);
        o.z = dd * (tot.z + self.z * dd);
        o.w = dd * (tot.w + self.w * dd);
        ax4[d * NF4 + lane] = o;
    }
}

// --- fused per-node MLP, register-weight version ---
// lane = output column j. W1[:,lane] (40), Wf[:,lane] (64), W2[lane,:] (3) in VGPRs.
// 4 nodes in flight (independent FMA chains); activations via uniform-addr b128 LDS.
__global__ __launch_bounds__(256) void k_node(
        const float4* __restrict__ ax4,
        const float* __restrict__ W1, const float* __restrict__ b1,
        const float* __restrict__ Wf, const float* __restrict__ bf,
        const float* __restrict__ W2, const float* __restrict__ dinv,
        float4* __restrict__ s2sp4, int n) {
    __shared__ float4 axb[4][NCHK * NF4];          // 5 KB per wave
    __shared__ float  hb[4][4][H];                 // 4 nodes in flight x 64
    int t = threadIdx.x, w = t >> 6, lane = t & 63;

    float w1c[NF];
    #pragma unroll
    for (int k = 0; k < NF; ++k) w1c[k] = W1[k * H + lane];
    float wfc[H];
    #pragma unroll
    for (int k = 0; k < H; ++k) wfc[k] = Wf[k * H + lane];
    float w20 = W2[lane * NC + 0], w21 = W2[lane * NC + 1], w22 = W2[lane * NC + 2];
    float b1l = b1[lane], bfl = bf[lane];

    int c0 = (blockIdx.x * 4 + w) * NCHK;
    if (c0 >= n) return;
    int cnt = min(NCHK, n - c0);

    for (int i = lane; i < cnt * NF4; i += 64)     // coalesced stage of 32 ax rows
        axb[w][i] = ax4[(size_t)c0 * NF4 + i];
    __threadfence_block();                         // order stage writes before reads

    for (int g = 0; g < NCHK; g += 4) {
        if (g >= cnt) break;
        // ---- layer 1: 4 interleaved nodes, uniform b128 activation reads ----
        float hA = b1l, hB = b1l, hC = b1l, hD = b1l;
        #pragma unroll
        for (int q = 0; q < NF4; ++q) {
            float4 aA = axb[w][(g + 0) * NF4 + q];
            float4 aB = axb[w][(g + 1) * NF4 + q];
            float4 aC = axb[w][(g + 2) * NF4 + q];
            float4 aD = axb[w][(g + 3) * NF4 + q];
            hA = fmaf(aA.x, w1c[4*q+0], hA); hB = fmaf(aB.x, w1c[4*q+0], hB);
            hC = fmaf(aC.x, w1c[4*q+0], hC); hD = fmaf(aD.x, w1c[4*q+0], hD);
            hA = fmaf(aA.y, w1c[4*q+1], hA); hB = fmaf(aB.y, w1c[4*q+1], hB);
            hC = fmaf(aC.y, w1c[4*q+1], hC); hD = fmaf(aD.y, w1c[4*q+1], hD);
            hA = fmaf(aA.z, w1c[4*q+2], hA); hB = fmaf(aB.z, w1c[4*q+2], hB);
            hC = fmaf(aC.z, w1c[4*q+2], hC); hD = fmaf(aD.z, w1c[4*q+2], hD);
            hA = fmaf(aA.w, w1c[4*q+3], hA); hB = fmaf(aB.w, w1c[4*q+3], hB);
            hC = fmaf(aC.w, w1c[4*q+3], hC); hD = fmaf(aD.w, w1c[4*q+3], hD);
        }
        hb[w][0][lane] = fmaxf(hA, 0.f);
        hb[w][1][lane] = fmaxf(hB, 0.f);
        hb[w][2][lane] = fmaxf(hC, 0.f);
        hb[w][3][lane] = fmaxf(hD, 0.f);
        __threadfence_block();
        // ---- layer 2 ----
        float mA = bfl, mB = bfl, mC = bfl, mD = bfl;
        #pragma unroll
        for (int q = 0; q < H / 4; ++q) {
            float4 xA = *(const float4*)&hb[w][0][q * 4];
            float4 xB = *(const float4*)&hb[w][1][q * 4];
            float4 xC = *(const float4*)&hb[w][2][q * 4];
            float4 xD = *(const float4*)&hb[w][3][q * 4];
            mA = fmaf(xA.x, wfc[4*q+0], mA); mB = fmaf(xB.x, wfc[4*q+0], mB);
            mC = fmaf(xC.x, wfc[4*q+0], mC); mD = fmaf(xD.x, wfc[4*q+0], mD);
            mA = fmaf(xA.y, wfc[4*q+1], mA); mB = fmaf(xB.y, wfc[4*q+1], mB);
            mC = fmaf(xC.y, wfc[4*q+1], mC); mD = fmaf(xD.y, wfc[4*q+1], mD);
            mA = fmaf(xA.z, wfc[4*q+2], mA); mB = fmaf(xB.z, wfc[4*q+2], mB);
            mC = fmaf(xC.z, wfc[4*q+2], mC); mD = fmaf(xD.z, wfc[4*q+2], mD);
            mA = fmaf(xA.w, wfc[4*q+3], mA); mB = fmaf(xB.w, wfc[4*q+3], mB);
            mC = fmaf(xC.w, wfc[4*q+3], mC); mD = fmaf(xD.w, wfc[4*q+3], mD);
        }
        __threadfence_block();                     // hb reads done before next writes
        float sA = (mA >= 0.5f) ? 1.f : 0.f;
        float sB = (mB >= 0.5f) ? 1.f : 0.f;
        float sC = (mC >= 0.5f) ? 1.f : 0.f;
        float sD = (mD >= 0.5f) ? 1.f : 0.f;
        float vv[12] = { sA * w20, sA * w21, sA * w22,  sB * w20, sB * w21, sB * w22,
                         sC * w20, sC * w21, sC * w22,  sD * w20, sD * w21, sD * w22 };
        #pragma unroll
        for (int r = 0; r < 12; ++r) {
            #pragma unroll
            for (int off = 32; off; off >>= 1)
                vv[r] += __shfl_down(vv[r], off);
        }
        if (lane == 0) {
            #pragma unroll
            for (int i = 0; i < 4; ++i) {
                if (g + i < cnt) {
                    float di = dinv[c0 + g + i];
                    s2sp4[c0 + g + i] =
                        make_float4(vv[i*3] * di, vv[i*3+1] * di, vv[i*3+2] * di, 0.f);
                }
            }
        }
    }
}

// --- pull conv2 + bias + filter; one float4 gather per neighbor ---
__global__ __launch_bounds__(256) void k_pull2(
        const unsigned* __restrict__ st, const int* __restrict__ rs,
        const int* __restrict__ rl, const float* __restrict__ dinv,
        const float4* __restrict__ s2sp4, const float* __restrict__ b2,
        const float* __restrict__ ef, float* __restrict__ out, int n) {
    int t = threadIdx.x;
    int w = t >> 6, lane = t & 63;
    int d = blockIdx.x * 4 + w;
    if (d >= n) return;
    int beg = rs[d], end = beg + rl[d];
    float a0 = 0.f, a1 = 0.f, a2 = 0.f;
    for (int j = beg + lane; j < end; j += 64) {
        float4 v = s2sp4[st[j] & SMASK];           // 1.6 MB: L2-resident gather
        a0 += v.x; a1 += v.y; a2 += v.z;
    }
    for (int off = 32; off; off >>= 1) {
        a0 += __shfl_down(a0, off);
        a1 += __shfl_down(a1, off);
        a2 += __shfl_down(a2, off);
    }
    if (lane == 0) {
        float dd = dinv[d];
        float4 self = s2sp4[d];
        out[d * NC + 0] = (dd * (a0 + self.x) + b2[0]) * ef[0];
        out[d * NC + 1] = (dd * (a1 + self.y) + b2[1]) * ef[1];
        out[d * NC + 2] = (dd * (a2 + self.z) + b2[2]) * ef[2];
    }
}

extern "C" void kernel_launch(void* const* d_in, const int* in_sizes, int n_in,
                              void* d_out, int out_size, void* d_ws, size_t ws_size,
                              hipStream_t stream) {
    const float* x  = (const float*)d_in[0];
    const int*   ei = (const int*)d_in[1];
    const float* W1 = (const float*)d_in[2];
    const float* b1 = (const float*)d_in[3];
    const float* Wf = (const float*)d_in[4];
    const float* bf = (const float*)d_in[5];
    const float* W2 = (const float*)d_in[6];
    const float* b2 = (const float*)d_in[7];
    const float* ef = (const float*)d_in[8];

    int n  = in_sizes[0] / NF;
    int ne = in_sizes[1] / 2;
    const int* src = ei;
    const int* dst = ei + ne;
    int nbk = (n + BK - 1) >> 8;                   // 391

    auto al = [](size_t v) { return (v + 255) & ~(size_t)255; };
    char* ws = (char*)d_ws;
    size_t off = 0;
    unsigned* staging = (unsigned*)(ws + off); off += al((size_t)nbk * CAP * 4);   // 16 MB
    float*    axbuf   = (float*)(ws + off);    off += al((size_t)n * NF * 4);      // 16 MB
    float*    s2sp    = (float*)(ws + off);    off += al((size_t)n * 4 * 4);
    float*    dinv    = (float*)(ws + off);    off += al((size_t)n * 4);
    int*      rsb     = (int*)(ws + off);      off += al((size_t)n * 4);
    int*      rlb     = (int*)(ws + off);      off += al((size_t)n * 4);
    int*      gcur    = (int*)(ws + off);      off += al((size_t)MAXNBK * 4);
    float* out = (float*)d_out;

    k_zero <<<2, 256, 0, stream>>>(gcur, MAXNBK);
    k_bin  <<<256, 1024, 0, stream>>>(src, dst, gcur, staging, ne, nbk);
    k_sort <<<nbk, 512, 0, stream>>>(staging, gcur, rsb, rlb, dinv, n);
    k_pull1<<<(n + 3) / 4, 256, 0, stream>>>(staging, rsb, rlb, dinv,
                                             (const float4*)x, (float4*)axbuf, n);
    k_node <<<(n + 4 * NCHK - 1) / (4 * NCHK), 256, 0, stream>>>(
        (const float4*)axbuf, W1, b1, Wf, bf, W2, dinv, (float4*)s2sp, n);
    k_pull2<<<(n + 3) / 4, 256, 0, stream>>>(staging, rsb, rlb, dinv, (const float4*)s2sp,
                                             b2, ef, out, n);
}

// Round 8
// 230.987 us; speedup vs baseline: 4.7411x; 1.1143x over previous
//
#include <hip/hip_runtime.h>

#define NF 40
#define NF4 10
#define H  64
#define NC 3
#define BK 256        // nodes per bucket (dst>>8)
#define CAP 10240     // staging capacity per bucket (mean 8192, +22 sigma)
#define MAXNBK 512
#define SMASK 0xFFFFFu
#define NSLC 16       // src slices in sort key
#define SSH 13        // slice = src>>13 (8192 nodes = 1.25 MB of x)

typedef float floatx4 __attribute__((ext_vector_type(4)));   // native vec for NT store

// --- zero ints ---
__global__ void k_zero(int* __restrict__ p, int n) {
    int i = blockIdx.x * blockDim.x + threadIdx.x;
    if (i < n) p[i] = 0;
}

// --- partition edges into fixed-capacity bucket streams; edges register-cached ---
__global__ __launch_bounds__(1024) void k_bin(const int* __restrict__ src,
                                              const int* __restrict__ dst,
                                              int* __restrict__ gcur,
                                              unsigned* __restrict__ staging,
                                              int ne, int nbk) {
    __shared__ int lh[MAXNBK];
    __shared__ int lcur[MAXNBK];
    int t = threadIdx.x;
    for (int b = t; b < nbk; b += 1024) lh[b] = 0;
    __syncthreads();
    int gtid = blockIdx.x * 1024 + t;
    int NT = gridDim.x * 1024;                     // 262144
    int bk[13]; unsigned ed[13];
    #pragma unroll
    for (int u = 0; u < 13; ++u) {                 // 13*262144 >= 3.2M: full coverage
        int i = gtid + u * NT;
        bool v = (i < ne);
        int dv = v ? dst[i] : 0;
        int sv = v ? src[i] : 0;
        bk[u] = v ? (dv >> 8) : -1;
        ed[u] = ((unsigned)(dv & 255) << 20) | (unsigned)sv;
        if (v) atomicAdd(&lh[dv >> 8], 1);
    }
    for (int i = gtid + 13 * NT; i < ne; i += NT)  // generic tail (0 iters here)
        atomicAdd(&lh[dst[i] >> 8], 1);
    __syncthreads();
    for (int b = t; b < nbk; b += 1024)
        lcur[b] = lh[b] ? atomicAdd(&gcur[b], lh[b]) : 0;   // reserve block's range
    __syncthreads();
    #pragma unroll
    for (int u = 0; u < 13; ++u) {
        if (bk[u] >= 0) {
            int p = atomicAdd(&lcur[bk[u]], 1);
            staging[(size_t)bk[u] * CAP + p] = ed[u];
        }
    }
    for (int i = gtid + 13 * NT; i < ne; i += NT) {
        int dv = dst[i], sv = src[i]; int b = dv >> 8;
        int p = atomicAdd(&lcur[b], 1);
        staging[(size_t)b * CAP + p] = ((unsigned)(dv & 255) << 20) | (unsigned)sv;
    }
}

// --- per-bucket sort by (dlocal, src-slice); emits rs/rl/dinv ---
// Slice-sorted lists make pull1's gathers sweep x in ~1.25 MB windows.
__global__ __launch_bounds__(512) void k_sort(unsigned* __restrict__ staging,
                                              const int* __restrict__ gcur,
                                              int* __restrict__ rs, int* __restrict__ rl,
                                              float* __restrict__ dinv, int n) {
    __shared__ unsigned buf[CAP];      // 40 KB bounce buffer
    __shared__ int cnt[BK * NSLC];     // 16 KB: histogram -> exclusive starts -> cursors
    __shared__ int tsum[512];
    int b = blockIdx.x, t = threadIdx.x;
    int ebase = b * CAP;
    int rlen = gcur[b];
    for (int j = t; j < rlen; j += 512) buf[j] = staging[ebase + j];
    for (int i = t; i < BK * NSLC; i += 512) cnt[i] = 0;
    __syncthreads();
    for (int j = t; j < rlen; j += 512) {
        unsigned e = buf[j];
        int key = ((int)(e >> 20) << 4) | (int)((e & SMASK) >> SSH);
        atomicAdd(&cnt[key], 1);
    }
    __syncthreads();
    // exclusive scan of cnt[4096]: per-thread serial 8 + Hillis-Steele over 512 totals
    int base8 = t * 8;
    int loc[8]; int run = 0;
    #pragma unroll
    for (int i = 0; i < 8; ++i) { loc[i] = run; run += cnt[base8 + i]; }
    tsum[t] = run;
    __syncthreads();
    for (int off = 1; off < 512; off <<= 1) {
        int a = (t >= off) ? tsum[t - off] : 0;
        __syncthreads();
        tsum[t] += a;
        __syncthreads();
    }
    int texcl = tsum[t] - run;
    #pragma unroll
    for (int i = 0; i < 8; ++i) cnt[base8 + i] = texcl + loc[i];
    __syncthreads();
    if (t < BK) {                                  // rs/rl/dinv before cursors bumped
        int node = b * BK + t;
        int st0 = cnt[t * NSLC];
        int en0 = (t == BK - 1) ? rlen : cnt[(t + 1) * NSLC];
        int deg = en0 - st0;
        if (node < n) {
            rs[node] = ebase + st0;
            rl[node] = deg;
            dinv[node] = rsqrtf((float)(deg + 1));
        }
    }
    __syncthreads();
    for (int j = t; j < rlen; j += 512) {          // scatter back sorted
        unsigned e = buf[j];
        int key = ((int)(e >> 20) << 4) | (int)((e & SMASK) >> SSH);
        int p = atomicAdd(&cnt[key], 1);
        staging[ebase + p] = e;
    }
}

// --- pull conv1: ax[d] = dd*(sum_s x[s]*dinv[s] + x[d]*dd); 6 nbr slots x 10 lanes ---
__global__ __launch_bounds__(256) void k_pull1(
        const unsigned* __restrict__ st, const int* __restrict__ rs,
        const int* __restrict__ rl, const float* __restrict__ dinv,
        const float4* __restrict__ x4, float* __restrict__ ax, int n) {
    __shared__ float4 red[4][64];
    int t = threadIdx.x;
    int w = t >> 6, lane = t & 63;
    int d = blockIdx.x * 4 + w;
    if (d >= n) return;
    int g = lane / 10, f = lane - g * 10;          // 6 slots x 10 float4-lanes
    int beg = rs[d], len = rl[d];
    float dd = dinv[d];
    float4 acc = make_float4(0.f, 0.f, 0.f, 0.f);
    if (g < 6) {
        int j = beg + g, end = beg + len;
        for (; j + 6 < end; j += 12) {             // 2 independent gathers in flight
            unsigned eA = __builtin_nontemporal_load(st + j);
            unsigned eB = __builtin_nontemporal_load(st + j + 6);
            int sA = (int)(eA & SMASK), sB = (int)(eB & SMASK);
            float wA = dinv[sA], wB = dinv[sB];
            float4 a4 = x4[sA * NF4 + f];
            float4 b4 = x4[sB * NF4 + f];
            acc.x += a4.x * wA + b4.x * wB;
            acc.y += a4.y * wA + b4.y * wB;
            acc.z += a4.z * wA + b4.z * wB;
            acc.w += a4.w * wA + b4.w * wB;
        }
        if (j < end) {
            unsigned e = __builtin_nontemporal_load(st + j);
            int s = (int)(e & SMASK);
            float wv = dinv[s];
            float4 v = x4[s * NF4 + f];
            acc.x += v.x * wv; acc.y += v.y * wv;
            acc.z += v.z * wv; acc.w += v.w * wv;
        }
    }
    red[w][lane] = acc;
    // same-wave LDS RAW: in-order DS pipe + compiler lgkmcnt; no block barrier needed
    if (lane < NF4) {
        float4 tot = red[w][lane];
        #pragma unroll
        for (int gg = 1; gg < 6; ++gg) {
            float4 r = red[w][gg * 10 + lane];
            tot.x += r.x; tot.y += r.y; tot.z += r.z; tot.w += r.w;
        }
        float4 self = x4[d * NF4 + lane];
        floatx4 o;
        o.x = dd * (tot.x + self.x * dd);
        o.y = dd * (tot.y + self.y * dd);
        o.z = dd * (tot.z + self.z * dd);
        o.w = dd * (tot.w + self.w * dd);
        __builtin_nontemporal_store(o, (floatx4*)(ax + (size_t)d * NF + 4 * lane));
    }
}

// --- fused per-node MLP: register-tiled wave-GEMM, 32 nodes x 64 cols per wave ---
// lane=(r,c): owns nodes 4r..4r+3, cols 8c..8c+7; acc[4][8]; 3 b128 LDS reads / 32 FMA.
__global__ __launch_bounds__(256, 2) void k_node(
        const float4* __restrict__ ax4,
        const float* __restrict__ W1, const float* __restrict__ b1,
        const float* __restrict__ Wf, const float* __restrict__ bf,
        const float* __restrict__ W2, const float* __restrict__ dinv,
        float4* __restrict__ s2sp4, int n) {
    __shared__ float lW1[NF * H];                  // 10 KB, [k][col] (native layout)
    __shared__ float lWf[H * H];                   // 16 KB, [k][col]
    __shared__ float hT[4][H * 32];                // 8 KB/wave; low NF*32 doubles as axT
    int t = threadIdx.x, w = t >> 6, lane = t & 63;
    int r = lane & 7, c = lane >> 3;

    for (int i = t; i < NF * H; i += 256) lW1[i] = W1[i];
    for (int i = t; i < H * H;  i += 256) lWf[i] = Wf[i];
    __syncthreads();                               // all waves pass before any returns

    int nb0 = (blockIdx.x * 4 + w) * 32;
    if (nb0 >= n) return;
    int cnt = min(32, n - nb0);

    float bb[8], bfv[8], w2s[8][3];
    #pragma unroll
    for (int j = 0; j < 8; ++j) {
        bb[j]  = b1[8 * c + j];
        bfv[j] = bf[8 * c + j];
        w2s[j][0] = W2[(8 * c + j) * NC + 0];
        w2s[j][1] = W2[(8 * c + j) * NC + 1];
        w2s[j][2] = W2[(8 * c + j) * NC + 2];
    }

    // stage ax rows (coalesced float4) transposed into axT[k][node] (= hT[w] low)
    float* axT = &hT[w][0];
    #pragma unroll
    for (int i = 0; i < 5; ++i) {
        int idx = lane + 64 * i;                   // 0..319 = 32 nodes x 10 float4
        int no = idx / NF4, q = idx - no * NF4;
        float4 a = make_float4(0.f, 0.f, 0.f, 0.f);
        if (no < cnt) a = ax4[(size_t)(nb0 + no) * NF4 + q];
        axT[(4 * q + 0) * 32 + no] = a.x;
        axT[(4 * q + 1) * 32 + no] = a.y;
        axT[(4 * q + 2) * 32 + no] = a.z;
        axT[(4 * q + 3) * 32 + no] = a.w;
    }
    // same-wave in-order DS: k-loop reads below see the staging writes

    // ---- layer 1: h = relu(ax*W1 + b1), K=40 ----
    float acc[4][8];
    #pragma unroll
    for (int i = 0; i < 4; ++i)
        #pragma unroll
        for (int j = 0; j < 8; ++j) acc[i][j] = bb[j];
    for (int k = 0; k < NF; ++k) {
        float4 a   = *(const float4*)&axT[k * 32 + 4 * r];
        float4 blo = *(const float4*)&lW1[k * H + 8 * c];
        float4 bhi = *(const float4*)&lW1[k * H + 8 * c + 4];
        float av[4] = {a.x, a.y, a.z, a.w};
        float bv[8] = {blo.x, blo.y, blo.z, blo.w, bhi.x, bhi.y, bhi.z, bhi.w};
        #pragma unroll
        for (int i = 0; i < 4; ++i)
            #pragma unroll
            for (int j = 0; j < 8; ++j) acc[i][j] = fmaf(av[i], bv[j], acc[i][j]);
    }
    // write h transposed (hT[j1][node]); all L1 reads completed (program order)
    #pragma unroll
    for (int j = 0; j < 8; ++j) {
        float4 hv = make_float4(fmaxf(acc[0][j], 0.f), fmaxf(acc[1][j], 0.f),
                                fmaxf(acc[2][j], 0.f), fmaxf(acc[3][j], 0.f));
        *(float4*)&hT[w][(8 * c + j) * 32 + 4 * r] = hv;
    }

    // ---- layer 2: mem = h*Wf + bf, K=64 ----
    float acc2[4][8];
    #pragma unroll
    for (int i = 0; i < 4; ++i)
        #pragma unroll
        for (int j = 0; j < 8; ++j) acc2[i][j] = bfv[j];
    for (int k = 0; k < H; ++k) {
        float4 a   = *(const float4*)&hT[w][k * 32 + 4 * r];
        float4 blo = *(const float4*)&lWf[k * H + 8 * c];
        float4 bhi = *(const float4*)&lWf[k * H + 8 * c + 4];
        float av[4] = {a.x, a.y, a.z, a.w};
        float bv[8] = {blo.x, blo.y, blo.z, blo.w, bhi.x, bhi.y, bhi.z, bhi.w};
        #pragma unroll
        for (int i = 0; i < 4; ++i)
            #pragma unroll
            for (int j = 0; j < 8; ++j) acc2[i][j] = fmaf(av[i], bv[j], acc2[i][j]);
    }

    // ---- spike + W2: per-lane partials over its 8 cols, xor-reduce over c ----
    float p0[4], p1[4], p2[4];
    #pragma unroll
    for (int i = 0; i < 4; ++i) { p0[i] = 0.f; p1[i] = 0.f; p2[i] = 0.f; }
    #pragma unroll
    for (int i = 0; i < 4; ++i)
        #pragma unroll
        for (int j = 0; j < 8; ++j) {
            float s = (acc2[i][j] >= 0.5f) ? 1.f : 0.f;
            p0[i] = fmaf(s, w2s[j][0], p0[i]);
            p1[i] = fmaf(s, w2s[j][1], p1[i]);
            p2[i] = fmaf(s, w2s[j][2], p2[i]);
        }
    #pragma unroll
    for (int off = 8; off < 64; off <<= 1) {
        #pragma unroll
        for (int i = 0; i < 4; ++i) {
            p0[i] += __shfl_xor(p0[i], off);
            p1[i] += __shfl_xor(p1[i], off);
            p2[i] += __shfl_xor(p2[i], off);
        }
    }
    if (c == 0) {
        #pragma unroll
        for (int i = 0; i < 4; ++i) {
            int no = 4 * r + i;
            if (no < cnt) {
                int node = nb0 + no;
                float di = dinv[node];
                s2sp4[node] = make_float4(p0[i] * di, p1[i] * di, p2[i] * di, 0.f);
            }
        }
    }
}

// --- pull conv2 + bias + filter; one float4 gather per neighbor ---
__global__ __launch_bounds__(256) void k_pull2(
        const unsigned* __restrict__ st, const int* __restrict__ rs,
        const int* __restrict__ rl, const float* __restrict__ dinv,
        const float4* __restrict__ s2sp4, const float* __restrict__ b2,
        const float* __restrict__ ef, float* __restrict__ out, int n) {
    int t = threadIdx.x;
    int w = t >> 6, lane = t & 63;
    int d = blockIdx.x * 4 + w;
    if (d >= n) return;
    int beg = rs[d], end = beg + rl[d];
    float a0 = 0.f, a1 = 0.f, a2 = 0.f;
    for (int j = beg + lane; j < end; j += 64) {
        unsigned e = __builtin_nontemporal_load(st + j);
        float4 v = s2sp4[e & SMASK];               // 1.6 MB: L2-resident gather
        a0 += v.x; a1 += v.y; a2 += v.z;
    }
    for (int off = 32; off; off >>= 1) {
        a0 += __shfl_down(a0, off);
        a1 += __shfl_down(a1, off);
        a2 += __shfl_down(a2, off);
    }
    if (lane == 0) {
        float dd = dinv[d];
        float4 self = s2sp4[d];
        out[d * NC + 0] = (dd * (a0 + self.x) + b2[0]) * ef[0];
        out[d * NC + 1] = (dd * (a1 + self.y) + b2[1]) * ef[1];
        out[d * NC + 2] = (dd * (a2 + self.z) + b2[2]) * ef[2];
    }
}

extern "C" void kernel_launch(void* const* d_in, const int* in_sizes, int n_in,
                              void* d_out, int out_size, void* d_ws, size_t ws_size,
                              hipStream_t stream) {
    const float* x  = (const float*)d_in[0];
    const int*   ei = (const int*)d_in[1];
    const float* W1 = (const float*)d_in[2];
    const float* b1 = (const float*)d_in[3];
    const float* Wf = (const float*)d_in[4];
    const float* bf = (const float*)d_in[5];
    const float* W2 = (const float*)d_in[6];
    const float* b2 = (const float*)d_in[7];
    const float* ef = (const float*)d_in[8];

    int n  = in_sizes[0] / NF;
    int ne = in_sizes[1] / 2;
    const int* src = ei;
    const int* dst = ei + ne;
    int nbk = (n + BK - 1) >> 8;                   // 391

    auto al = [](size_t v) { return (v + 255) & ~(size_t)255; };
    char* ws = (char*)d_ws;
    size_t off = 0;
    unsigned* staging = (unsigned*)(ws + off); off += al((size_t)nbk * CAP * 4);   // 16 MB
    float*    axbuf   = (float*)(ws + off);    off += al((size_t)n * NF * 4);      // 16 MB
    float*    s2sp    = (float*)(ws + off);    off += al((size_t)n * 4 * 4);
    float*    dinv    = (float*)(ws + off);    off += al((size_t)n * 4);
    int*      rsb     = (int*)(ws + off);      off += al((size_t)n * 4);
    int*      rlb     = (int*)(ws + off);      off += al((size_t)n * 4);
    int*      gcur    = (int*)(ws + off);      off += al((size_t)MAXNBK * 4);
    float* out = (float*)d_out;

    k_zero <<<2, 256, 0, stream>>>(gcur, MAXNBK);
    k_bin  <<<256, 1024, 0, stream>>>(src, dst, gcur, staging, ne, nbk);
    k_sort <<<nbk, 512, 0, stream>>>(staging, gcur, rsb, rlb, dinv, n);
    k_pull1<<<(n + 3) / 4, 256, 0, stream>>>(staging, rsb, rlb, dinv,
                                             (const float4*)x, axbuf, n);
    k_node <<<(n + 127) / 128, 256, 0, stream>>>(
        (const float4*)axbuf, W1, b1, Wf, bf, W2, dinv, (float4*)s2sp, n);
    k_pull2<<<(n + 3) / 4, 256, 0, stream>>>(staging, rsb, rlb, dinv, (const float4*)s2sp,
                                             b2, ef, out, n);
}

// Round 9
// 214.178 us; speedup vs baseline: 5.1131x; 1.0785x over previous
//
#include <hip/hip_runtime.h>

#define NF 40
#define NF4 10
#define H  64
#define NC 3
#define BK 256        // nodes per bucket (dst>>8)
#define CAP 10240     // staging capacity per bucket (mean 8192, +22 sigma)
#define MAXNBK 512
#define SMASK 0xFFFFFu
#define EPB 6400      // edges per k_bin2 block

// --- zero ints ---
__global__ void k_zero(int* __restrict__ p, int n) {
    int i = blockIdx.x * blockDim.x + threadIdx.x;
    if (i < n) p[i] = 0;
}

// --- partition: block-local bucket sort in LDS, then coalesced window writes ---
__global__ __launch_bounds__(512) void k_bin2(const int* __restrict__ src,
                                              const int* __restrict__ dst,
                                              int* __restrict__ gcur,
                                              unsigned* __restrict__ staging,
                                              int ne, int nbk) {
    __shared__ unsigned sorted[EPB];               // 25.6 KB
    __shared__ unsigned short sbk[EPB];            // 12.8 KB
    __shared__ int cnt[MAXNBK];
    __shared__ int tsum[MAXNBK];
    __shared__ int lstart[MAXNBK];
    __shared__ int gbase[MAXNBK];
    __shared__ int cur[MAXNBK];
    int t = threadIdx.x;
    int e0 = blockIdx.x * EPB;
    int m = min(EPB, ne - e0);
    if (m <= 0) return;

    for (int b = t; b < MAXNBK; b += 512) cnt[b] = 0;
    __syncthreads();
    for (int j = t; j < m; j += 512)               // pass 1: bucket histogram
        atomicAdd(&cnt[dst[e0 + j] >> 8], 1);
    __syncthreads();
    int val = (t < nbk) ? cnt[t] : 0;              // block-wide exclusive scan (512)
    tsum[t] = val;
    __syncthreads();
    for (int off = 1; off < 512; off <<= 1) {
        int a = (t >= off) ? tsum[t - off] : 0;
        __syncthreads();
        tsum[t] += a;
        __syncthreads();
    }
    lstart[t] = tsum[t] - val;
    cur[t] = tsum[t] - val;
    if (t < nbk) gbase[t] = val ? atomicAdd(&gcur[t], val) : 0;   // reserve windows
    __syncthreads();
    for (int j = t; j < m; j += 512) {             // pass 2: LDS scatter (bucket order)
        int d = dst[e0 + j], s = src[e0 + j];
        int b = d >> 8;
        int p = atomicAdd(&cur[b], 1);
        sorted[p] = ((unsigned)(d & 255) << 20) | (unsigned)s;
        sbk[p] = (unsigned short)b;
    }
    __syncthreads();
    for (int j = t; j < m; j += 512) {             // pass 3: near-coalesced writes
        int b = sbk[j];
        staging[(size_t)b * CAP + gbase[b] + (j - lstart[b])] = sorted[j];
    }
}

// --- per-bucket sort by dlocal (in place via LDS bounce); emits rs/rl/dinv ---
__global__ __launch_bounds__(512) void k_sort(unsigned* __restrict__ staging,
                                              const int* __restrict__ gcur,
                                              int* __restrict__ rs, int* __restrict__ rl,
                                              float* __restrict__ dinv, int n) {
    __shared__ unsigned buf[CAP];      // 40 KB bounce buffer
    __shared__ int cnt[BK];
    __shared__ int scn[BK];
    __shared__ int cur[BK];
    int b = blockIdx.x, t = threadIdx.x;
    int ebase = b * CAP;
    int rlen = gcur[b];
    for (int j = t; j < rlen; j += 512) buf[j] = staging[ebase + j];
    if (t < BK) cnt[t] = 0;
    __syncthreads();
    for (int j = t; j < rlen; j += 512)
        atomicAdd(&cnt[buf[j] >> 20], 1);
    __syncthreads();
    if (t < BK) scn[t] = cnt[t];
    __syncthreads();
    for (int off = 1; off < BK; off <<= 1) {       // inclusive Hillis-Steele
        int a = (t < BK && t >= off) ? scn[t - off] : 0;
        __syncthreads();
        if (t < BK) scn[t] += a;
        __syncthreads();
    }
    if (t < BK) {
        int deg = cnt[t];
        int excl = scn[t] - deg;
        cur[t] = excl;
        int node = b * BK + t;
        if (node < n) {
            rs[node] = ebase + excl;
            rl[node] = deg;
            dinv[node] = rsqrtf((float)(deg + 1));
        }
    }
    __syncthreads();
    for (int j = t; j < rlen; j += 512) {          // scatter back sorted by dlocal
        unsigned e = buf[j];
        int p = atomicAdd(&cur[e >> 20], 1);
        staging[ebase + p] = e;
    }
}

// --- pull conv1: ax[d] = dd*(sum_s x[s]*dinv[s] + x[d]*dd); 6 nbr slots x 10 lanes ---
__global__ __launch_bounds__(256) void k_pull1(
        const unsigned* __restrict__ st, const int* __restrict__ rs,
        const int* __restrict__ rl, const float* __restrict__ dinv,
        const float4* __restrict__ x4, float4* __restrict__ ax4, int n) {
    __shared__ float4 red[4][64];
    int t = threadIdx.x;
    int w = t >> 6, lane = t & 63;
    int d = blockIdx.x * 4 + w;
    if (d >= n) return;
    int g = lane / 10, f = lane - g * 10;          // 6 slots x 10 float4-lanes
    int beg = rs[d], len = rl[d];
    float dd = dinv[d];
    float4 acc = make_float4(0.f, 0.f, 0.f, 0.f);
    if (g < 6) {
        int j = beg + g, end = beg + len;
        for (; j + 6 < end; j += 12) {             // 2 independent gathers in flight
            unsigned eA = st[j], eB = st[j + 6];
            int sA = (int)(eA & SMASK), sB = (int)(eB & SMASK);
            float wA = dinv[sA], wB = dinv[sB];
            float4 a4 = x4[sA * NF4 + f];
            float4 b4 = x4[sB * NF4 + f];
            acc.x += a4.x * wA + b4.x * wB;
            acc.y += a4.y * wA + b4.y * wB;
            acc.z += a4.z * wA + b4.z * wB;
            acc.w += a4.w * wA + b4.w * wB;
        }
        if (j < end) {
            unsigned e = st[j];
            int s = (int)(e & SMASK);
            float wv = dinv[s];
            float4 v = x4[s * NF4 + f];
            acc.x += v.x * wv; acc.y += v.y * wv;
            acc.z += v.z * wv; acc.w += v.w * wv;
        }
    }
    red[w][lane] = acc;
    // same-wave LDS RAW: in-order DS pipe + compiler lgkmcnt; no block barrier needed
    if (lane < NF4) {
        float4 tot = red[w][lane];
        #pragma unroll
        for (int gg = 1; gg < 6; ++gg) {
            float4 r = red[w][gg * 10 + lane];
            tot.x += r.x; tot.y += r.y; tot.z += r.z; tot.w += r.w;
        }
        float4 self = x4[d * NF4 + lane];
        float4 o;
        o.x = dd * (tot.x + self.x * dd);
        o.y = dd * (tot.y + self.y * dd);
        o.z = dd * (tot.z + self.z * dd);
        o.w = dd * (tot.w + self.w * dd);
        ax4[d * NF4 + lane] = o;
    }
}

// --- fused per-node MLP: register-tiled wave-GEMM, 32 nodes x 64 cols per wave ---
// lane=(r,c): owns nodes 4r..4r+3, cols 8c..8c+7; acc[4][8]; 3 b128 LDS reads / 32 FMA.
__global__ __launch_bounds__(256, 2) void k_node(
        const float4* __restrict__ ax4,
        const float* __restrict__ W1, const float* __restrict__ b1,
        const float* __restrict__ Wf, const float* __restrict__ bf,
        const float* __restrict__ W2, const float* __restrict__ dinv,
        float4* __restrict__ s2sp4, int n) {
    __shared__ float lW1[NF * H];                  // 10 KB, [k][col] (native layout)
    __shared__ float lWf[H * H];                   // 16 KB, [k][col]
    __shared__ float hT[4][H * 32];                // 8 KB/wave; low NF*32 doubles as axT
    int t = threadIdx.x, w = t >> 6, lane = t & 63;
    int r = lane & 7, c = lane >> 3;

    for (int i = t; i < NF * H; i += 256) lW1[i] = W1[i];
    for (int i = t; i < H * H;  i += 256) lWf[i] = Wf[i];
    __syncthreads();                               // all waves pass before any returns

    int nb0 = (blockIdx.x * 4 + w) * 32;
    if (nb0 >= n) return;
    int cnt = min(32, n - nb0);

    float bb[8], bfv[8], w2s[8][3];
    #pragma unroll
    for (int j = 0; j < 8; ++j) {
        bb[j]  = b1[8 * c + j];
        bfv[j] = bf[8 * c + j];
        w2s[j][0] = W2[(8 * c + j) * NC + 0];
        w2s[j][1] = W2[(8 * c + j) * NC + 1];
        w2s[j][2] = W2[(8 * c + j) * NC + 2];
    }

    // stage ax rows (coalesced float4) transposed into axT[k][node] (= hT[w] low)
    float* axT = &hT[w][0];
    #pragma unroll
    for (int i = 0; i < 5; ++i) {
        int idx = lane + 64 * i;                   // 0..319 = 32 nodes x 10 float4
        int no = idx / NF4, q = idx - no * NF4;
        float4 a = make_float4(0.f, 0.f, 0.f, 0.f);
        if (no < cnt) a = ax4[(size_t)(nb0 + no) * NF4 + q];
        axT[(4 * q + 0) * 32 + no] = a.x;
        axT[(4 * q + 1) * 32 + no] = a.y;
        axT[(4 * q + 2) * 32 + no] = a.z;
        axT[(4 * q + 3) * 32 + no] = a.w;
    }
    // same-wave in-order DS: k-loop reads below see the staging writes

    // ---- layer 1: h = relu(ax*W1 + b1), K=40 ----
    float acc[4][8];
    #pragma unroll
    for (int i = 0; i < 4; ++i)
        #pragma unroll
        for (int j = 0; j < 8; ++j) acc[i][j] = bb[j];
    for (int k = 0; k < NF; ++k) {
        float4 a   = *(const float4*)&axT[k * 32 + 4 * r];
        float4 blo = *(const float4*)&lW1[k * H + 8 * c];
        float4 bhi = *(const float4*)&lW1[k * H + 8 * c + 4];
        float av[4] = {a.x, a.y, a.z, a.w};
        float bv[8] = {blo.x, blo.y, blo.z, blo.w, bhi.x, bhi.y, bhi.z, bhi.w};
        #pragma unroll
        for (int i = 0; i < 4; ++i)
            #pragma unroll
            for (int j = 0; j < 8; ++j) acc[i][j] = fmaf(av[i], bv[j], acc[i][j]);
    }
    // write h transposed (hT[j1][node]); all L1 reads completed (program order)
    #pragma unroll
    for (int j = 0; j < 8; ++j) {
        float4 hv = make_float4(fmaxf(acc[0][j], 0.f), fmaxf(acc[1][j], 0.f),
                                fmaxf(acc[2][j], 0.f), fmaxf(acc[3][j], 0.f));
        *(float4*)&hT[w][(8 * c + j) * 32 + 4 * r] = hv;
    }

    // ---- layer 2: mem = h*Wf + bf, K=64 ----
    float acc2[4][8];
    #pragma unroll
    for (int i = 0; i < 4; ++i)
        #pragma unroll
        for (int j = 0; j < 8; ++j) acc2[i][j] = bfv[j];
    for (int k = 0; k < H; ++k) {
        float4 a   = *(const float4*)&hT[w][k * 32 + 4 * r];
        float4 blo = *(const float4*)&lWf[k * H + 8 * c];
        float4 bhi = *(const float4*)&lWf[k * H + 8 * c + 4];
        float av[4] = {a.x, a.y, a.z, a.w};
        float bv[8] = {blo.x, blo.y, blo.z, blo.w, bhi.x, bhi.y, bhi.z, bhi.w};
        #pragma unroll
        for (int i = 0; i < 4; ++i)
            #pragma unroll
            for (int j = 0; j < 8; ++j) acc2[i][j] = fmaf(av[i], bv[j], acc2[i][j]);
    }

    // ---- spike + W2: per-lane partials over its 8 cols, xor-reduce over c ----
    float p0[4], p1[4], p2[4];
    #pragma unroll
    for (int i = 0; i < 4; ++i) { p0[i] = 0.f; p1[i] = 0.f; p2[i] = 0.f; }
    #pragma unroll
    for (int i = 0; i < 4; ++i)
        #pragma unroll
        for (int j = 0; j < 8; ++j) {
            float s = (acc2[i][j] >= 0.5f) ? 1.f : 0.f;
            p0[i] = fmaf(s, w2s[j][0], p0[i]);
            p1[i] = fmaf(s, w2s[j][1], p1[i]);
            p2[i] = fmaf(s, w2s[j][2], p2[i]);
        }
    #pragma unroll
    for (int off = 8; off < 64; off <<= 1) {
        #pragma unroll
        for (int i = 0; i < 4; ++i) {
            p0[i] += __shfl_xor(p0[i], off);
            p1[i] += __shfl_xor(p1[i], off);
            p2[i] += __shfl_xor(p2[i], off);
        }
    }
    if (c == 0) {
        #pragma unroll
        for (int i = 0; i < 4; ++i) {
            int no = 4 * r + i;
            if (no < cnt) {
                int node = nb0 + no;
                float di = dinv[node];
                s2sp4[node] = make_float4(p0[i] * di, p1[i] * di, p2[i] * di, 0.f);
            }
        }
    }
}

// --- pull conv2 + bias + filter; one float4 gather per neighbor ---
__global__ __launch_bounds__(256) void k_pull2(
        const unsigned* __restrict__ st, const int* __restrict__ rs,
        const int* __restrict__ rl, const float* __restrict__ dinv,
        const float4* __restrict__ s2sp4, const float* __restrict__ b2,
        const float* __restrict__ ef, float* __restrict__ out, int n) {
    int t = threadIdx.x;
    int w = t >> 6, lane = t & 63;
    int d = blockIdx.x * 4 + w;
    if (d >= n) return;
    int beg = rs[d], end = beg + rl[d];
    float a0 = 0.f, a1 = 0.f, a2 = 0.f;
    for (int j = beg + lane; j < end; j += 64) {
        float4 v = s2sp4[st[j] & SMASK];           // 1.6 MB: L2-resident gather
        a0 += v.x; a1 += v.y; a2 += v.z;
    }
    for (int off = 32; off; off >>= 1) {
        a0 += __shfl_down(a0, off);
        a1 += __shfl_down(a1, off);
        a2 += __shfl_down(a2, off);
    }
    if (lane == 0) {
        float dd = dinv[d];
        float4 self = s2sp4[d];
        out[d * NC + 0] = (dd * (a0 + self.x) + b2[0]) * ef[0];
        out[d * NC + 1] = (dd * (a1 + self.y) + b2[1]) * ef[1];
        out[d * NC + 2] = (dd * (a2 + self.z) + b2[2]) * ef[2];
    }
}

extern "C" void kernel_launch(void* const* d_in, const int* in_sizes, int n_in,
                              void* d_out, int out_size, void* d_ws, size_t ws_size,
                              hipStream_t stream) {
    const float* x  = (const float*)d_in[0];
    const int*   ei = (const int*)d_in[1];
    const float* W1 = (const float*)d_in[2];
    const float* b1 = (const float*)d_in[3];
    const float* Wf = (const float*)d_in[4];
    const float* bf = (const float*)d_in[5];
    const float* W2 = (const float*)d_in[6];
    const float* b2 = (const float*)d_in[7];
    const float* ef = (const float*)d_in[8];

    int n  = in_sizes[0] / NF;
    int ne = in_sizes[1] / 2;
    const int* src = ei;
    const int* dst = ei + ne;
    int nbk = (n + BK - 1) >> 8;                   // 391

    auto al = [](size_t v) { return (v + 255) & ~(size_t)255; };
    char* ws = (char*)d_ws;
    size_t off = 0;
    unsigned* staging = (unsigned*)(ws + off); off += al((size_t)nbk * CAP * 4);   // 16 MB
    float*    axbuf   = (float*)(ws + off);    off += al((size_t)n * NF * 4);      // 16 MB
    float*    s2sp    = (float*)(ws + off);    off += al((size_t)n * 4 * 4);
    float*    dinv    = (float*)(ws + off);    off += al((size_t)n * 4);
    int*      rsb     = (int*)(ws + off);      off += al((size_t)n * 4);
    int*      rlb     = (int*)(ws + off);      off += al((size_t)n * 4);
    int*      gcur    = (int*)(ws + off);      off += al((size_t)MAXNBK * 4);
    float* out = (float*)d_out;

    int binblocks = (ne + EPB - 1) / EPB;          // 500

    k_zero <<<2, 256, 0, stream>>>(gcur, MAXNBK);
    k_bin2 <<<binblocks, 512, 0, stream>>>(src, dst, gcur, staging, ne, nbk);
    k_sort <<<nbk, 512, 0, stream>>>(staging, gcur, rsb, rlb, dinv, n);
    k_pull1<<<(n + 3) / 4, 256, 0, stream>>>(staging, rsb, rlb, dinv,
                                             (const float4*)x, (float4*)axbuf, n);
    k_node <<<(n + 127) / 128, 256, 0, stream>>>(
        (const float4*)axbuf, W1, b1, Wf, bf, W2, dinv, (float4*)s2sp, n);
    k_pull2<<<(n + 3) / 4, 256, 0, stream>>>(staging, rsb, rlb, dinv, (const float4*)s2sp,
                                             b2, ef, out, n);
}